// Round 2
// 243.005 us; speedup vs baseline: 1.0175x; 1.0175x over previous
//
#include <hip/hip_runtime.h>

// y[i] = (x[i]*W0 >= x[i]*W1) ? -1.0f : +1.0f
// (argmax over [x*W0, x*W1] with first-max tie-break, then 2*idx-1)
// Memory-bound elementwise op: float4 loads/stores, one vec4 per thread.
//
// This revision: nontemporal loads/stores (nt cache flag). The 302 MB
// read+write footprint exceeds the 256 MB Infinity Cache; bypassing
// L2/MALL insertion avoids read/write stream thrash. Predicate left
// bit-identical to the verified version (absmax = 0).
//
// NOTE: __builtin_nontemporal_* rejects HIP_vector_type structs; use a
// clang native ext_vector_type(4) (identical 16B layout) for the access.

typedef float floatx4 __attribute__((ext_vector_type(4)));

__global__ __launch_bounds__(256) void metaconv_sign4(
    const floatx4* __restrict__ x4,
    const float* __restrict__ W,
    floatx4* __restrict__ out4,
    int n4)
{
    int i = blockIdx.x * blockDim.x + threadIdx.x;
    // Wave-uniform scalar loads; L1/L2-resident after first touch.
    float w0 = W[0];
    float w1 = W[1];
    if (i < n4) {
        floatx4 v = __builtin_nontemporal_load(&x4[i]);
        floatx4 r;
        r.x = (v.x * w0 >= v.x * w1) ? -1.0f : 1.0f;
        r.y = (v.y * w0 >= v.y * w1) ? -1.0f : 1.0f;
        r.z = (v.z * w0 >= v.z * w1) ? -1.0f : 1.0f;
        r.w = (v.w * w0 >= v.w * w1) ? -1.0f : 1.0f;
        __builtin_nontemporal_store(r, &out4[i]);
    }
}

__global__ void metaconv_sign_tail(
    const float* __restrict__ x,
    const float* __restrict__ W,
    float* __restrict__ out,
    int start, int n)
{
    int i = start + blockIdx.x * blockDim.x + threadIdx.x;
    float w0 = W[0];
    float w1 = W[1];
    if (i < n) {
        float v = x[i];
        out[i] = (v * w0 >= v * w1) ? -1.0f : 1.0f;
    }
}

extern "C" void kernel_launch(void* const* d_in, const int* in_sizes, int n_in,
                              void* d_out, int out_size, void* d_ws, size_t ws_size,
                              hipStream_t stream)
{
    const float* x = (const float*)d_in[0];
    const float* W = (const float*)d_in[1];
    float* out = (float*)d_out;

    int n = in_sizes[0];          // 2048*2048*3*3 = 37,748,736
    int n4 = n >> 2;              // float4 count (n divisible by 4 here)
    int rem = n & 3;

    if (n4 > 0) {
        const int block = 256;
        int grid = (n4 + block - 1) / block;
        metaconv_sign4<<<grid, block, 0, stream>>>(
            (const floatx4*)x, W, (floatx4*)out, n4);
    }
    if (rem > 0) {
        metaconv_sign_tail<<<1, 64, 0, stream>>>(x, W, out, n4 << 2, n);
    }
}